// Round 17
// baseline (55.755 us; speedup 1.0000x reference)
//
#include <hip/hip_runtime.h>
#include <hip/hip_fp16.h>
#include <math.h>

// Problem constants (fixed by the harness's setup_inputs)
#define HDIM 256
#define NDIM 64
#define LDIM 8192
#define LF   4097          // L/2 + 1
#define MDIM 4096          // L/2  (complex FFT size)
#define LOG2M 12
#define TWN  2048          // twiddle table: e^{+i*pi*q/2048}

typedef _Float16 f16x8 __attribute__((ext_vector_type(8)));
typedef float    f32x4 __attribute__((ext_vector_type(4)));

// round-nearest f32 pair -> packed f16 dword
__device__ __forceinline__ int cvt_pk_f16(float lo, float hi) {
    union { __half2 h; int i; } u;
    u.h = __floats2half2_rn(lo, hi);
    return u.i;
}

// index padding (kept from R16; conflict fix deferred)
__device__ __forceinline__ int spad(int i) { return i + (i >> 4); }

// ---------------------------------------------------------------------------
// R17: FUSED cauchy + irfft, LDS cut 102.9 -> 52.2 KB => 2 blocks/CU
//      (8 waves/SIMD during the latency-bound cauchy phase, was 4).
//   (1) kfs aliased onto S: pack reads its inputs to registers, barrier,
//       writes bit-reversed Z into the same buffer.
//   (2) TW = 2048 entries e^{+i*pi*q/2048} (butterflies need only these);
//       pack twiddles e^{+i*pi*l/4096} via 1 sincosf + pi/4 rotation.
//   Cauchy math unchanged from R16 (MFMA f16, RN packs, z-substitution).
// ---------------------------------------------------------------------------
__global__ __launch_bounds__(1024, 8) void fused_kernel(
    const float* __restrict__ log_dt,
    const float* __restrict__ C_re, const float* __restrict__ C_im,
    const float* __restrict__ B_re, const float* __restrict__ B_im,
    const float* __restrict__ P_re, const float* __restrict__ P_im,
    const float* __restrict__ Q_re, const float* __restrict__ Q_im,
    const float* __restrict__ w_re, const float* __restrict__ w_im,
    float2* __restrict__ out2)
{
    __shared__ float2 S[MDIM + MDIM / 16 + 1];   // 34.8 KB (kf + Z share it)
    __shared__ float2 TW[TWN + TWN / 16];        // 17.4 KB

    const int h    = blockIdx.x;
    const int tid  = threadIdx.x;
    const int lane = tid & 63;
    const int wave = tid >> 6;
    const int g    = lane >> 4;     // k-block index (0..3)
    const int m    = lane & 15;     // col (l-offset) and A-row index
    const float dt = expf(log_dt[h]);
    const int hb   = h * NDIM;

    // ---- twiddle table: TW[q] = e^{+i*pi*q/2048}, q in [0,2048) ----
    {
        float s, c;
        sincosf((3.14159265358979323846f / (float)TWN) * (float)tid, &s, &c);
        TW[spad(tid)] = make_float2(c, s);
        sincosf((3.14159265358979323846f / (float)TWN) * (float)(tid + 1024), &s, &c);
        TW[spad(tid + 1024)] = make_float2(c, s);
    }

    // ---- Nyquist bin (l = 4096): k_f = 0.5*dt*sum_n v00[n] ----
    if (tid < 64) {
        const float br = B_re[hb + lane], bi = B_im[hb + lane];
        const float cr = C_re[hb + lane], ci = C_im[hb + lane];
        float sr = cr * br - ci * bi;
        float si = cr * bi + ci * br;
        #pragma unroll
        for (int off = 32; off > 0; off >>= 1) {
            sr += __shfl_xor(sr, off);
            si += __shfl_xor(si, off);
        }
        if (tid == 0)
            S[spad(MDIM)] = make_float2(0.5f * dt * sr, 0.5f * dt * si);
    }

    // ---- per-lane constants: pole params for this lane's 16 n + A frags ----
    float nwr_[16], nw2_[16], wi_[16];
    int   av[4][4];                 // A fragment dwords (2 f16 each)
    {
        const bool arow = (m < 8);
        const int  ai   = m >> 1;   // 0:C*B 1:C*P 2:Q*B 3:Q*P
        const int  c    = m & 1;    // 0:re-row 1:im-row
        const float* fre = (ai >= 2) ? Q_re : C_re;
        const float* fim = (ai >= 2) ? Q_im : C_im;
        const float* sre = (ai & 1) ? P_re : B_re;
        const float* sim = (ai & 1) ? P_im : B_im;
        #pragma unroll
        for (int q = 0; q < 4; ++q) {
            #pragma unroll
            for (int t = 0; t < 4; ++t) {
                const int n = hb + 16 * q + 4 * g + t;
                const float nw = -w_re[n] * dt;    // > 0
                nwr_[q * 4 + t] = nw;
                nw2_[q * 4 + t] = nw * nw;
                wi_[q * 4 + t]  = w_im[n] * dt;
                float e0 = 0.f, e1 = 0.f;
                if (arow) {
                    const float fr = fre[n], fi = fim[n];
                    const float s2r = sre[n], s2i = sim[n];
                    const float vr = fr * s2r - fi * s2i;
                    const float vi = fr * s2i + fi * s2r;
                    e0 = c ? vi : vr;
                    e1 = c ? vr : -vi;
                }
                av[q][t] = cvt_pk_f16(e0, e1);
            }
        }
    }

    // ---- cauchy phase: wave owns l = wave*256 + t*16 + m, t = 0..15 ----
    const int lbase = wave * 256 + m;

    float ch, sh;   // half-angle state: cos/sin(pi*l/8192)
    {
        const float a0 = (3.14159265358979323846f / (float)LDIM) * (float)lbase;
        sincosf(a0, &sh, &ch);
    }
    const float cd = 0.99998117528260114265f;   // cos(pi/512)
    const float sd = 0.00613588464915447536f;   // sin(pi/512)

    #pragma unroll 2
    for (int t16 = 0; t16 < 16; ++t16) {
        const float zt = 2.f * sh * __builtin_amdgcn_rcpf(ch);  // 2 tan(th/2)

        f32x4 acc0 = {0.f, 0.f, 0.f, 0.f};
        f32x4 acc1 = {0.f, 0.f, 0.f, 0.f};
        #pragma unroll
        for (int q = 0; q < 4; ++q) {
            int bv[4];
            #pragma unroll
            for (int t = 0; t < 4; ++t) {
                const float tim = zt - wi_[q * 4 + t];     // Im(z - wdt)
                const float den = fmaf(tim, tim, nw2_[q * 4 + t]);
                const float rc  = __builtin_amdgcn_rcpf(den);
                bv[t] = cvt_pk_f16(nwr_[q * 4 + t] * rc, -(tim * rc));
            }
            union { int i[4]; f16x8 v; } ua, ub;
            ua.i[0] = av[q][0]; ua.i[1] = av[q][1];
            ua.i[2] = av[q][2]; ua.i[3] = av[q][3];
            ub.i[0] = bv[0]; ub.i[1] = bv[1]; ub.i[2] = bv[2]; ub.i[3] = bv[3];
            if (q < 2)
                acc0 = __builtin_amdgcn_mfma_f32_16x16x32_f16(ua.v, ub.v, acc0, 0, 0, 0);
            else
                acc1 = __builtin_amdgcn_mfma_f32_16x16x32_f16(ua.v, ub.v, acc1, 0, 0, 0);
        }
        const f32x4 acc = acc0 + acc1;

        // epilogue: lanes 0-15 hold V00,V01; 16-31 hold V10,V11
        const float o0 = __shfl_xor(acc[0], 16);
        const float o1 = __shfl_xor(acc[1], 16);
        const float o2 = __shfl_xor(acc[2], 16);
        const float o3 = __shfl_xor(acc[3], 16);
        if (lane < 16) {
            const int l = lbase + t16 * 16;
            const float numr = acc[2] * o0 - acc[3] * o1;
            const float numi = acc[2] * o1 + acc[3] * o0;
            const float d_r  = 1.f + dt * o2;
            const float d_i  = dt * o3;
            const float dd   = fmaf(d_r, d_r, d_i * d_i);
            const float rr2  = __builtin_amdgcn_rcpf(dd);
            const float cr = dt * ((numr * d_r + numi * d_i) * rr2);
            const float ci = dt * ((numi * d_r - numr * d_i) * rr2);
            const float Tr = acc[0] - cr;
            const float Ti = acc[1] - ci;
            const float Ei = 0.5f * dt * zt;            // E = dt*(1, zt/2)
            S[spad(l)] = make_float2(dt * Tr - Ei * Ti, dt * Ti + Ei * Tr);
        }

        // rotate half-angle state by pi/512 (16 l-steps)
        const float chn = ch * cd - sh * sd;
        const float shn = sh * cd + ch * sd;
        ch = chn; sh = shn;
    }

    __syncthreads();

    // ---- pack phase (aliased): read kf values to registers ----
    const int l0 = tid;            // 0..1023
    const int l1 = tid + 1024;     // 1024..2047
    const float2 Kl0 = S[spad(l0)];
    const float2 Km0 = S[spad(MDIM - l0)];   // l0=0 -> Nyquist cell
    const float2 Kl1 = S[spad(l1)];
    const float2 Km1 = S[spad(MDIM - l1)];
    float2 K2;
    if (tid == 0) K2 = S[spad(2048)];

    // pack twiddles: w0 = e^{+i*pi*l0/4096}; w1 = w0 * e^{+i*pi/4}
    float w0s, w0c;
    sincosf((3.14159265358979323846f / (float)MDIM) * (float)l0, &w0s, &w0c);
    const float r2 = 0.70710678118654752440f;
    const float w1c = (w0c - w0s) * r2;
    const float w1s = (w0s + w0c) * r2;

    __syncthreads();

    // ---- write bit-reversed Z into S (in place) ----
    {
        // l0 slot
        const float Ar = 0.5f * (Kl0.x + Km0.x);
        const float Ai = 0.5f * (Kl0.y - Km0.y);
        const float Br = 0.5f * (Kl0.x - Km0.x);
        const float Bi = 0.5f * (Kl0.y + Km0.y);
        const float Or = w0c * Br - w0s * Bi;
        const float Oi = w0c * Bi + w0s * Br;
        const int bl = (int)(__brev((unsigned)l0) >> (32 - LOG2M));
        S[spad(bl)] = make_float2(Ar - Oi, Ai + Or);
        if (l0 > 0) {
            const int bm = (int)(__brev((unsigned)(MDIM - l0)) >> (32 - LOG2M));
            S[spad(bm)] = make_float2(Ar + Oi, Or - Ai);
        }
    }
    {
        // l1 slot
        const float Ar = 0.5f * (Kl1.x + Km1.x);
        const float Ai = 0.5f * (Kl1.y - Km1.y);
        const float Br = 0.5f * (Kl1.x - Km1.x);
        const float Bi = 0.5f * (Kl1.y + Km1.y);
        const float Or = w1c * Br - w1s * Bi;
        const float Oi = w1c * Bi + w1s * Br;
        const int bl = (int)(__brev((unsigned)l1) >> (32 - LOG2M));
        S[spad(bl)] = make_float2(Ar - Oi, Ai + Or);
        const int bm = (int)(__brev((unsigned)(MDIM - l1)) >> (32 - LOG2M));
        S[spad(bm)] = make_float2(Ar + Oi, Or - Ai);
    }
    if (tid == 0) {
        // l = 2048: w = e^{i*pi/2} = (0,1) -> Z = (K.x, -K.y); rev(2048) = 1
        S[spad(1)] = make_float2(K2.x, -K2.y);
    }

    // ---- 12 radix-2 DIT stages, inverse twiddles from the table ----
    #pragma unroll
    for (int stage = 0; stage < LOG2M; ++stage) {
        const int half = 1 << stage;
        __syncthreads();
        #pragma unroll 2
        for (int t = tid; t < MDIM / 2; t += 1024) {
            const int pos = t & (half - 1);
            const int i0  = ((t & ~(half - 1)) << 1) | pos;
            const int i1  = i0 + half;
            const float2 w = TW[spad(pos << (LOG2M - 1 - stage))]; // e^{+i pi pos/half}
            const float2 a = S[spad(i0)];
            const float2 b = S[spad(i1)];
            const float tr = w.x * b.x - w.y * b.y;
            const float ti = w.x * b.y + w.y * b.x;
            S[spad(i0)] = make_float2(a.x + tr, a.y + ti);
            S[spad(i1)] = make_float2(a.x - tr, a.y - ti);
        }
    }
    __syncthreads();

    const float invM = 1.f / (float)MDIM;
    for (int n = tid; n < MDIM; n += 1024) {
        const float2 z = S[spad(n)];
        out2[(size_t)h * MDIM + n] = make_float2(z.x * invM, z.y * invM);
    }
}

extern "C" void kernel_launch(void* const* d_in, const int* in_sizes, int n_in,
                              void* d_out, int out_size, void* d_ws, size_t ws_size,
                              hipStream_t stream)
{
    const float* log_dt = (const float*)d_in[0];
    const float* C_re   = (const float*)d_in[1];
    const float* C_im   = (const float*)d_in[2];
    const float* B_re   = (const float*)d_in[3];
    const float* B_im   = (const float*)d_in[4];
    const float* P_re   = (const float*)d_in[5];
    const float* P_im   = (const float*)d_in[6];
    const float* Q_re   = (const float*)d_in[7];
    const float* Q_im   = (const float*)d_in[8];
    const float* w_re   = (const float*)d_in[9];
    const float* w_im   = (const float*)d_in[10];

    float2* out2 = (float2*)d_out;

    fused_kernel<<<HDIM, 1024, 0, stream>>>(log_dt, C_re, C_im, B_re, B_im,
                                            P_re, P_im, Q_re, Q_im,
                                            w_re, w_im, out2);
}

// Round 18
// 38.751 us; speedup vs baseline: 1.4388x; 1.4388x over previous
//
#include <hip/hip_runtime.h>
#include <hip/hip_fp16.h>
#include <math.h>

// Problem constants (fixed by the harness's setup_inputs)
#define HDIM 256
#define NDIM 64
#define LDIM 8192
#define LF   4097          // L/2 + 1
#define MDIM 4096          // L/2  (complex FFT size)
#define LOG2M 12
#define TWN  2048          // twiddle table: e^{+i*pi*q/2048}

typedef _Float16 f16x8 __attribute__((ext_vector_type(8)));
typedef float    f32x4 __attribute__((ext_vector_type(4)));

// round-nearest f32 pair -> packed f16 dword
__device__ __forceinline__ int cvt_pk_f16(float lo, float hi) {
    union { __half2 h; int i; } u;
    u.h = __floats2half2_rn(lo, hi);
    return u.i;
}

// index padding (conflict mitigation; full fix deferred)
__device__ __forceinline__ int spad(int i) { return i + (i >> 4); }

// ---------------------------------------------------------------------------
// R18 = R17's LDS layout (52.2 KB: kfs aliased onto S, TW=2048) with the
// launch bound reverted to (1024, 4). R17's (1024,8) forced VGPR cap = 32
// (512 regs / 16 waves-per-SIMD) -> spilled the 48-dword constant set
// (FETCH 22MB / WRITE 52MB scratch traffic). At ~52 VGPR the HW gives
// 2 blocks/CU (wave-limited) = 8 waves/SIMD without constraining the
// allocator: LDS limit 3 blocks, wave limit 2 blocks, VGPR 52 fits 8/SIMD.
// ---------------------------------------------------------------------------
__global__ __launch_bounds__(1024, 4) void fused_kernel(
    const float* __restrict__ log_dt,
    const float* __restrict__ C_re, const float* __restrict__ C_im,
    const float* __restrict__ B_re, const float* __restrict__ B_im,
    const float* __restrict__ P_re, const float* __restrict__ P_im,
    const float* __restrict__ Q_re, const float* __restrict__ Q_im,
    const float* __restrict__ w_re, const float* __restrict__ w_im,
    float2* __restrict__ out2)
{
    __shared__ float2 S[MDIM + MDIM / 16 + 1];   // 34.8 KB (kf + Z share it)
    __shared__ float2 TW[TWN + TWN / 16];        // 17.4 KB

    const int h    = blockIdx.x;
    const int tid  = threadIdx.x;
    const int lane = tid & 63;
    const int wave = tid >> 6;
    const int g    = lane >> 4;     // k-block index (0..3)
    const int m    = lane & 15;     // col (l-offset) and A-row index
    const float dt = expf(log_dt[h]);
    const int hb   = h * NDIM;

    // ---- twiddle table: TW[q] = e^{+i*pi*q/2048}, q in [0,2048) ----
    {
        float s, c;
        sincosf((3.14159265358979323846f / (float)TWN) * (float)tid, &s, &c);
        TW[spad(tid)] = make_float2(c, s);
        sincosf((3.14159265358979323846f / (float)TWN) * (float)(tid + 1024), &s, &c);
        TW[spad(tid + 1024)] = make_float2(c, s);
    }

    // ---- Nyquist bin (l = 4096): k_f = 0.5*dt*sum_n v00[n] ----
    if (tid < 64) {
        const float br = B_re[hb + lane], bi = B_im[hb + lane];
        const float cr = C_re[hb + lane], ci = C_im[hb + lane];
        float sr = cr * br - ci * bi;
        float si = cr * bi + ci * br;
        #pragma unroll
        for (int off = 32; off > 0; off >>= 1) {
            sr += __shfl_xor(sr, off);
            si += __shfl_xor(si, off);
        }
        if (tid == 0)
            S[spad(MDIM)] = make_float2(0.5f * dt * sr, 0.5f * dt * si);
    }

    // ---- per-lane constants: pole params for this lane's 16 n + A frags ----
    float nwr_[16], nw2_[16], wi_[16];
    int   av[4][4];                 // A fragment dwords (2 f16 each)
    {
        const bool arow = (m < 8);
        const int  ai   = m >> 1;   // 0:C*B 1:C*P 2:Q*B 3:Q*P
        const int  c    = m & 1;    // 0:re-row 1:im-row
        const float* fre = (ai >= 2) ? Q_re : C_re;
        const float* fim = (ai >= 2) ? Q_im : C_im;
        const float* sre = (ai & 1) ? P_re : B_re;
        const float* sim = (ai & 1) ? P_im : B_im;
        #pragma unroll
        for (int q = 0; q < 4; ++q) {
            #pragma unroll
            for (int t = 0; t < 4; ++t) {
                const int n = hb + 16 * q + 4 * g + t;
                const float nw = -w_re[n] * dt;    // > 0
                nwr_[q * 4 + t] = nw;
                nw2_[q * 4 + t] = nw * nw;
                wi_[q * 4 + t]  = w_im[n] * dt;
                float e0 = 0.f, e1 = 0.f;
                if (arow) {
                    const float fr = fre[n], fi = fim[n];
                    const float s2r = sre[n], s2i = sim[n];
                    const float vr = fr * s2r - fi * s2i;
                    const float vi = fr * s2i + fi * s2r;
                    e0 = c ? vi : vr;
                    e1 = c ? vr : -vi;
                }
                av[q][t] = cvt_pk_f16(e0, e1);
            }
        }
    }

    // ---- cauchy phase: wave owns l = wave*256 + t*16 + m, t = 0..15 ----
    const int lbase = wave * 256 + m;

    float ch, sh;   // half-angle state: cos/sin(pi*l/8192)
    {
        const float a0 = (3.14159265358979323846f / (float)LDIM) * (float)lbase;
        sincosf(a0, &sh, &ch);
    }
    const float cd = 0.99998117528260114265f;   // cos(pi/512)
    const float sd = 0.00613588464915447536f;   // sin(pi/512)

    #pragma unroll 2
    for (int t16 = 0; t16 < 16; ++t16) {
        const float zt = 2.f * sh * __builtin_amdgcn_rcpf(ch);  // 2 tan(th/2)

        f32x4 acc0 = {0.f, 0.f, 0.f, 0.f};
        f32x4 acc1 = {0.f, 0.f, 0.f, 0.f};
        #pragma unroll
        for (int q = 0; q < 4; ++q) {
            int bv[4];
            #pragma unroll
            for (int t = 0; t < 4; ++t) {
                const float tim = zt - wi_[q * 4 + t];     // Im(z - wdt)
                const float den = fmaf(tim, tim, nw2_[q * 4 + t]);
                const float rc  = __builtin_amdgcn_rcpf(den);
                bv[t] = cvt_pk_f16(nwr_[q * 4 + t] * rc, -(tim * rc));
            }
            union { int i[4]; f16x8 v; } ua, ub;
            ua.i[0] = av[q][0]; ua.i[1] = av[q][1];
            ua.i[2] = av[q][2]; ua.i[3] = av[q][3];
            ub.i[0] = bv[0]; ub.i[1] = bv[1]; ub.i[2] = bv[2]; ub.i[3] = bv[3];
            if (q < 2)
                acc0 = __builtin_amdgcn_mfma_f32_16x16x32_f16(ua.v, ub.v, acc0, 0, 0, 0);
            else
                acc1 = __builtin_amdgcn_mfma_f32_16x16x32_f16(ua.v, ub.v, acc1, 0, 0, 0);
        }
        const f32x4 acc = acc0 + acc1;

        // epilogue: lanes 0-15 hold V00,V01; 16-31 hold V10,V11
        const float o0 = __shfl_xor(acc[0], 16);
        const float o1 = __shfl_xor(acc[1], 16);
        const float o2 = __shfl_xor(acc[2], 16);
        const float o3 = __shfl_xor(acc[3], 16);
        if (lane < 16) {
            const int l = lbase + t16 * 16;
            const float numr = acc[2] * o0 - acc[3] * o1;
            const float numi = acc[2] * o1 + acc[3] * o0;
            const float d_r  = 1.f + dt * o2;
            const float d_i  = dt * o3;
            const float dd   = fmaf(d_r, d_r, d_i * d_i);
            const float rr2  = __builtin_amdgcn_rcpf(dd);
            const float cr = dt * ((numr * d_r + numi * d_i) * rr2);
            const float ci = dt * ((numi * d_r - numr * d_i) * rr2);
            const float Tr = acc[0] - cr;
            const float Ti = acc[1] - ci;
            const float Ei = 0.5f * dt * zt;            // E = dt*(1, zt/2)
            S[spad(l)] = make_float2(dt * Tr - Ei * Ti, dt * Ti + Ei * Tr);
        }

        // rotate half-angle state by pi/512 (16 l-steps)
        const float chn = ch * cd - sh * sd;
        const float shn = sh * cd + ch * sd;
        ch = chn; sh = shn;
    }

    __syncthreads();

    // ---- pack phase (aliased): read kf values to registers ----
    const int l0 = tid;            // 0..1023
    const int l1 = tid + 1024;     // 1024..2047
    const float2 Kl0 = S[spad(l0)];
    const float2 Km0 = S[spad(MDIM - l0)];   // l0=0 -> Nyquist cell
    const float2 Kl1 = S[spad(l1)];
    const float2 Km1 = S[spad(MDIM - l1)];
    float2 K2;
    if (tid == 0) K2 = S[spad(2048)];

    // pack twiddles: w0 = e^{+i*pi*l0/4096}; w1 = w0 * e^{+i*pi/4}
    float w0s, w0c;
    sincosf((3.14159265358979323846f / (float)MDIM) * (float)l0, &w0s, &w0c);
    const float r2 = 0.70710678118654752440f;
    const float w1c = (w0c - w0s) * r2;
    const float w1s = (w0s + w0c) * r2;

    __syncthreads();

    // ---- write bit-reversed Z into S (in place) ----
    {
        // l0 slot
        const float Ar = 0.5f * (Kl0.x + Km0.x);
        const float Ai = 0.5f * (Kl0.y - Km0.y);
        const float Br = 0.5f * (Kl0.x - Km0.x);
        const float Bi = 0.5f * (Kl0.y + Km0.y);
        const float Or = w0c * Br - w0s * Bi;
        const float Oi = w0c * Bi + w0s * Br;
        const int bl = (int)(__brev((unsigned)l0) >> (32 - LOG2M));
        S[spad(bl)] = make_float2(Ar - Oi, Ai + Or);
        if (l0 > 0) {
            const int bm = (int)(__brev((unsigned)(MDIM - l0)) >> (32 - LOG2M));
            S[spad(bm)] = make_float2(Ar + Oi, Or - Ai);
        }
    }
    {
        // l1 slot
        const float Ar = 0.5f * (Kl1.x + Km1.x);
        const float Ai = 0.5f * (Kl1.y - Km1.y);
        const float Br = 0.5f * (Kl1.x - Km1.x);
        const float Bi = 0.5f * (Kl1.y + Km1.y);
        const float Or = w1c * Br - w1s * Bi;
        const float Oi = w1c * Bi + w1s * Br;
        const int bl = (int)(__brev((unsigned)l1) >> (32 - LOG2M));
        S[spad(bl)] = make_float2(Ar - Oi, Ai + Or);
        const int bm = (int)(__brev((unsigned)(MDIM - l1)) >> (32 - LOG2M));
        S[spad(bm)] = make_float2(Ar + Oi, Or - Ai);
    }
    if (tid == 0) {
        // l = 2048: w = e^{i*pi/2} = (0,1) -> Z = (K.x, -K.y); rev(2048) = 1
        S[spad(1)] = make_float2(K2.x, -K2.y);
    }

    // ---- 12 radix-2 DIT stages, inverse twiddles from the table ----
    #pragma unroll
    for (int stage = 0; stage < LOG2M; ++stage) {
        const int half = 1 << stage;
        __syncthreads();
        #pragma unroll 2
        for (int t = tid; t < MDIM / 2; t += 1024) {
            const int pos = t & (half - 1);
            const int i0  = ((t & ~(half - 1)) << 1) | pos;
            const int i1  = i0 + half;
            const float2 w = TW[spad(pos << (LOG2M - 1 - stage))]; // e^{+i pi pos/half}
            const float2 a = S[spad(i0)];
            const float2 b = S[spad(i1)];
            const float tr = w.x * b.x - w.y * b.y;
            const float ti = w.x * b.y + w.y * b.x;
            S[spad(i0)] = make_float2(a.x + tr, a.y + ti);
            S[spad(i1)] = make_float2(a.x - tr, a.y - ti);
        }
    }
    __syncthreads();

    const float invM = 1.f / (float)MDIM;
    for (int n = tid; n < MDIM; n += 1024) {
        const float2 z = S[spad(n)];
        out2[(size_t)h * MDIM + n] = make_float2(z.x * invM, z.y * invM);
    }
}

extern "C" void kernel_launch(void* const* d_in, const int* in_sizes, int n_in,
                              void* d_out, int out_size, void* d_ws, size_t ws_size,
                              hipStream_t stream)
{
    const float* log_dt = (const float*)d_in[0];
    const float* C_re   = (const float*)d_in[1];
    const float* C_im   = (const float*)d_in[2];
    const float* B_re   = (const float*)d_in[3];
    const float* B_im   = (const float*)d_in[4];
    const float* P_re   = (const float*)d_in[5];
    const float* P_im   = (const float*)d_in[6];
    const float* Q_re   = (const float*)d_in[7];
    const float* Q_im   = (const float*)d_in[8];
    const float* w_re   = (const float*)d_in[9];
    const float* w_im   = (const float*)d_in[10];

    float2* out2 = (float2*)d_out;

    fused_kernel<<<HDIM, 1024, 0, stream>>>(log_dt, C_re, C_im, B_re, B_im,
                                            P_re, P_im, Q_re, Q_im,
                                            w_re, w_im, out2);
}

// Round 19
// 37.093 us; speedup vs baseline: 1.5031x; 1.0447x over previous
//
#include <hip/hip_runtime.h>
#include <hip/hip_fp16.h>
#include <math.h>

// Problem constants (fixed by the harness's setup_inputs)
#define HDIM 256
#define NDIM 64
#define LDIM 8192
#define LF   4097          // L/2 + 1
#define MDIM 4096          // L/2  (complex FFT size)
#define LOG2M 12
#define TWN  2048          // twiddle table: e^{+i*pi*q/2048}

typedef _Float16 f16x8 __attribute__((ext_vector_type(8)));
typedef float    f32x4 __attribute__((ext_vector_type(4)));

// round-nearest f32 pair -> packed f16 dword
__device__ __forceinline__ int cvt_pk_f16(float lo, float hi) {
    union { __half2 h; int i; } u;
    u.h = __floats2half2_rn(lo, hi);
    return u.i;
}

// XOR bank swizzle (bijective on low 4 bits; consistent across all accesses).
// Spreads stride-64 (bit-rev scatter), stride-2 (early stages), and strided
// TW reads across bank-pairs — the additive pad provably failed on these.
__device__ __forceinline__ int swz(int i) {
    return i ^ (((i >> 4) ^ (i >> 8)) & 15);
}

// ---------------------------------------------------------------------------
// R19 = R18 + (1) XOR swizzle replacing additive pad on S and TW,
//             (2) pair-wise rcp in the B-build (1 v_rcp per 2 poles),
//             (3) 1/M folded into the cauchy epilogue's E factor.
// Structure unchanged: fused cauchy(MFMA f16)+irfft, 1024 thr/block, 1 head
// per block, kfs aliased onto S, TW=2048, launch_bounds(1024,4).
// ---------------------------------------------------------------------------
__global__ __launch_bounds__(1024, 4) void fused_kernel(
    const float* __restrict__ log_dt,
    const float* __restrict__ C_re, const float* __restrict__ C_im,
    const float* __restrict__ B_re, const float* __restrict__ B_im,
    const float* __restrict__ P_re, const float* __restrict__ P_im,
    const float* __restrict__ Q_re, const float* __restrict__ Q_im,
    const float* __restrict__ w_re, const float* __restrict__ w_im,
    float2* __restrict__ out2)
{
    __shared__ float2 S[MDIM + 1];   // 32.8 KB (kf and Z share it; swizzled)
    __shared__ float2 TW[TWN];       // 16.4 KB (swizzled)

    const int h    = blockIdx.x;
    const int tid  = threadIdx.x;
    const int lane = tid & 63;
    const int wave = tid >> 6;
    const int g    = lane >> 4;     // k-block index (0..3)
    const int m    = lane & 15;     // col (l-offset) and A-row index
    const float dt = expf(log_dt[h]);
    const float dtM = dt * (1.f / (float)MDIM);   // dt/M (E-factor scale)
    const int hb   = h * NDIM;

    // ---- twiddle table: TW[q] = e^{+i*pi*q/2048}, q in [0,2048) ----
    {
        float s, c;
        sincosf((3.14159265358979323846f / (float)TWN) * (float)tid, &s, &c);
        TW[swz(tid)] = make_float2(c, s);
        sincosf((3.14159265358979323846f / (float)TWN) * (float)(tid + 1024), &s, &c);
        TW[swz(tid + 1024)] = make_float2(c, s);
    }

    // ---- Nyquist bin (l = 4096): k_f = 0.5*(dt/M)*sum_n v00[n] ----
    if (tid < 64) {
        const float br = B_re[hb + lane], bi = B_im[hb + lane];
        const float cr = C_re[hb + lane], ci = C_im[hb + lane];
        float sr = cr * br - ci * bi;
        float si = cr * bi + ci * br;
        #pragma unroll
        for (int off = 32; off > 0; off >>= 1) {
            sr += __shfl_xor(sr, off);
            si += __shfl_xor(si, off);
        }
        if (tid == 0)
            S[swz(MDIM)] = make_float2(0.5f * dtM * sr, 0.5f * dtM * si);
    }

    // ---- per-lane constants: pole params for this lane's 16 n + A frags ----
    float nwr_[16], nw2_[16], wi_[16];
    int   av[4][4];                 // A fragment dwords (2 f16 each)
    {
        const bool arow = (m < 8);
        const int  ai   = m >> 1;   // 0:C*B 1:C*P 2:Q*B 3:Q*P
        const int  c    = m & 1;    // 0:re-row 1:im-row
        const float* fre = (ai >= 2) ? Q_re : C_re;
        const float* fim = (ai >= 2) ? Q_im : C_im;
        const float* sre = (ai & 1) ? P_re : B_re;
        const float* sim = (ai & 1) ? P_im : B_im;
        #pragma unroll
        for (int q = 0; q < 4; ++q) {
            #pragma unroll
            for (int t = 0; t < 4; ++t) {
                const int n = hb + 16 * q + 4 * g + t;
                const float nw = -w_re[n] * dt;    // > 0
                nwr_[q * 4 + t] = nw;
                nw2_[q * 4 + t] = nw * nw;
                wi_[q * 4 + t]  = w_im[n] * dt;
                float e0 = 0.f, e1 = 0.f;
                if (arow) {
                    const float fr = fre[n], fi = fim[n];
                    const float s2r = sre[n], s2i = sim[n];
                    const float vr = fr * s2r - fi * s2i;
                    const float vi = fr * s2i + fi * s2r;
                    e0 = c ? vi : vr;
                    e1 = c ? vr : -vi;
                }
                av[q][t] = cvt_pk_f16(e0, e1);
            }
        }
    }

    // ---- cauchy phase: wave owns l = wave*256 + t*16 + m, t = 0..15 ----
    const int lbase = wave * 256 + m;

    float ch, sh;   // half-angle state: cos/sin(pi*l/8192)
    {
        const float a0 = (3.14159265358979323846f / (float)LDIM) * (float)lbase;
        sincosf(a0, &sh, &ch);
    }
    const float cd = 0.99998117528260114265f;   // cos(pi/512)
    const float sd = 0.00613588464915447536f;   // sin(pi/512)

    #pragma unroll 2
    for (int t16 = 0; t16 < 16; ++t16) {
        const float zt = 2.f * sh * __builtin_amdgcn_rcpf(ch);  // 2 tan(th/2)

        f32x4 acc0 = {0.f, 0.f, 0.f, 0.f};
        f32x4 acc1 = {0.f, 0.f, 0.f, 0.f};
        #pragma unroll
        for (int q = 0; q < 4; ++q) {
            // B-build with pair-wise rcp: 1 v_rcp per 2 poles
            float den[4], tim[4];
            #pragma unroll
            for (int t = 0; t < 4; ++t) {
                tim[t] = zt - wi_[q * 4 + t];            // Im(z - wdt)
                den[t] = fmaf(tim[t], tim[t], nw2_[q * 4 + t]);
            }
            const float p01 = den[0] * den[1];
            const float p23 = den[2] * den[3];
            const float rp01 = __builtin_amdgcn_rcpf(p01);
            const float rp23 = __builtin_amdgcn_rcpf(p23);
            const float rc0 = rp01 * den[1], rc1 = rp01 * den[0];
            const float rc2 = rp23 * den[3], rc3 = rp23 * den[2];

            int bv[4];
            bv[0] = cvt_pk_f16(nwr_[q * 4 + 0] * rc0, -(tim[0] * rc0));
            bv[1] = cvt_pk_f16(nwr_[q * 4 + 1] * rc1, -(tim[1] * rc1));
            bv[2] = cvt_pk_f16(nwr_[q * 4 + 2] * rc2, -(tim[2] * rc2));
            bv[3] = cvt_pk_f16(nwr_[q * 4 + 3] * rc3, -(tim[3] * rc3));

            union { int i[4]; f16x8 v; } ua, ub;
            ua.i[0] = av[q][0]; ua.i[1] = av[q][1];
            ua.i[2] = av[q][2]; ua.i[3] = av[q][3];
            ub.i[0] = bv[0]; ub.i[1] = bv[1]; ub.i[2] = bv[2]; ub.i[3] = bv[3];
            if (q < 2)
                acc0 = __builtin_amdgcn_mfma_f32_16x16x32_f16(ua.v, ub.v, acc0, 0, 0, 0);
            else
                acc1 = __builtin_amdgcn_mfma_f32_16x16x32_f16(ua.v, ub.v, acc1, 0, 0, 0);
        }
        const f32x4 acc = acc0 + acc1;

        // epilogue: lanes 0-15 hold V00,V01; 16-31 hold V10,V11
        const float o0 = __shfl_xor(acc[0], 16);
        const float o1 = __shfl_xor(acc[1], 16);
        const float o2 = __shfl_xor(acc[2], 16);
        const float o3 = __shfl_xor(acc[3], 16);
        if (lane < 16) {
            const int l = lbase + t16 * 16;
            const float numr = acc[2] * o0 - acc[3] * o1;
            const float numi = acc[2] * o1 + acc[3] * o0;
            const float d_r  = 1.f + dt * o2;
            const float d_i  = dt * o3;
            const float dd   = fmaf(d_r, d_r, d_i * d_i);
            const float rr2  = __builtin_amdgcn_rcpf(dd);
            const float cr = dt * ((numr * d_r + numi * d_i) * rr2);
            const float ci = dt * ((numi * d_r - numr * d_i) * rr2);
            const float Tr = acc[0] - cr;
            const float Ti = acc[1] - ci;
            // E = (dt/M) * (1, zt/2)  — 1/M folded here, final store is a copy
            const float Ei = 0.5f * dtM * zt;
            S[swz(l)] = make_float2(dtM * Tr - Ei * Ti, dtM * Ti + Ei * Tr);
        }

        // rotate half-angle state by pi/512 (16 l-steps)
        const float chn = ch * cd - sh * sd;
        const float shn = sh * cd + ch * sd;
        ch = chn; sh = shn;
    }

    __syncthreads();

    // ---- pack phase (aliased): read kf values to registers ----
    const int l0 = tid;            // 0..1023
    const int l1 = tid + 1024;     // 1024..2047
    const float2 Kl0 = S[swz(l0)];
    const float2 Km0 = S[swz(MDIM - l0)];   // l0=0 -> Nyquist cell
    const float2 Kl1 = S[swz(l1)];
    const float2 Km1 = S[swz(MDIM - l1)];
    float2 K2;
    if (tid == 0) K2 = S[swz(2048)];

    // pack twiddles: w0 = e^{+i*pi*l0/4096}; w1 = w0 * e^{+i*pi/4}
    float w0s, w0c;
    sincosf((3.14159265358979323846f / (float)MDIM) * (float)l0, &w0s, &w0c);
    const float r2 = 0.70710678118654752440f;
    const float w1c = (w0c - w0s) * r2;
    const float w1s = (w0s + w0c) * r2;

    __syncthreads();

    // ---- write bit-reversed Z into S (in place) ----
    {
        // l0 slot
        const float Ar = 0.5f * (Kl0.x + Km0.x);
        const float Ai = 0.5f * (Kl0.y - Km0.y);
        const float Br = 0.5f * (Kl0.x - Km0.x);
        const float Bi = 0.5f * (Kl0.y + Km0.y);
        const float Or = w0c * Br - w0s * Bi;
        const float Oi = w0c * Bi + w0s * Br;
        const int bl = (int)(__brev((unsigned)l0) >> (32 - LOG2M));
        S[swz(bl)] = make_float2(Ar - Oi, Ai + Or);
        if (l0 > 0) {
            const int bm = (int)(__brev((unsigned)(MDIM - l0)) >> (32 - LOG2M));
            S[swz(bm)] = make_float2(Ar + Oi, Or - Ai);
        }
    }
    {
        // l1 slot
        const float Ar = 0.5f * (Kl1.x + Km1.x);
        const float Ai = 0.5f * (Kl1.y - Km1.y);
        const float Br = 0.5f * (Kl1.x - Km1.x);
        const float Bi = 0.5f * (Kl1.y + Km1.y);
        const float Or = w1c * Br - w1s * Bi;
        const float Oi = w1c * Bi + w1s * Br;
        const int bl = (int)(__brev((unsigned)l1) >> (32 - LOG2M));
        S[swz(bl)] = make_float2(Ar - Oi, Ai + Or);
        const int bm = (int)(__brev((unsigned)(MDIM - l1)) >> (32 - LOG2M));
        S[swz(bm)] = make_float2(Ar + Oi, Or - Ai);
    }
    if (tid == 0) {
        // l = 2048: w = e^{i*pi/2} = (0,1) -> Z = (K.x, -K.y); rev(2048) = 1
        S[swz(1)] = make_float2(K2.x, -K2.y);
    }

    // ---- 12 radix-2 DIT stages, inverse twiddles from the table ----
    #pragma unroll
    for (int stage = 0; stage < LOG2M; ++stage) {
        const int half = 1 << stage;
        __syncthreads();
        #pragma unroll 2
        for (int t = tid; t < MDIM / 2; t += 1024) {
            const int pos = t & (half - 1);
            const int i0  = ((t & ~(half - 1)) << 1) | pos;
            const int i1  = i0 + half;
            const float2 w = TW[swz(pos << (LOG2M - 1 - stage))]; // e^{+i pi pos/half}
            const float2 a = S[swz(i0)];
            const float2 b = S[swz(i1)];
            const float tr = w.x * b.x - w.y * b.y;
            const float ti = w.x * b.y + w.y * b.x;
            S[swz(i0)] = make_float2(a.x + tr, a.y + ti);
            S[swz(i1)] = make_float2(a.x - tr, a.y - ti);
        }
    }
    __syncthreads();

    // ---- final store: plain copy (1/M already folded into E) ----
    for (int n = tid; n < MDIM; n += 1024) {
        out2[(size_t)h * MDIM + n] = S[swz(n)];
    }
}

extern "C" void kernel_launch(void* const* d_in, const int* in_sizes, int n_in,
                              void* d_out, int out_size, void* d_ws, size_t ws_size,
                              hipStream_t stream)
{
    const float* log_dt = (const float*)d_in[0];
    const float* C_re   = (const float*)d_in[1];
    const float* C_im   = (const float*)d_in[2];
    const float* B_re   = (const float*)d_in[3];
    const float* B_im   = (const float*)d_in[4];
    const float* P_re   = (const float*)d_in[5];
    const float* P_im   = (const float*)d_in[6];
    const float* Q_re   = (const float*)d_in[7];
    const float* Q_im   = (const float*)d_in[8];
    const float* w_re   = (const float*)d_in[9];
    const float* w_im   = (const float*)d_in[10];

    float2* out2 = (float2*)d_out;

    fused_kernel<<<HDIM, 1024, 0, stream>>>(log_dt, C_re, C_im, B_re, B_im,
                                            P_re, P_im, Q_re, Q_im,
                                            w_re, w_im, out2);
}